// Round 3
// baseline (550.130 us; speedup 1.0000x reference)
//
#include <hip/hip_runtime.h>

// Node2Edge2Node GNN block, MI355X (gfx950) — R6: structural fusion.
//
//   agg[v] = (Σ_{e->v} x[src_e]) @ W1a  +  cnt_v * (x[v] @ W1b)
//          + (Σ_{e->v} ea_e)    @ W1c  +  cnt_v * b1
//   out    = [agg | x] @ W2 + b2
//
// R6: ~394 us/iter is harness workspace poison (2x 1.31GB fills, fixed).
// Controllable ~126 us was 7 kernels; floor is the 327MB ea stream (~55us).
// Structural changes, no numeric changes:
//  - Slotted CSR (stride 192/node; P(deg>192)~1e-30 for Poisson(64)) kills
//    the global scan + row_ptr entirely.
//  - k_sum+k_out fused: 512-thread block owns 32 nodes; segment-sums land
//    directly in the LDS GEMM tile (bf16 once — same rounding as before),
//    deleting the 20.4MB sx/sea round-trip.
//  - hist fused into prep (independent work, one launch).
// Pipeline: k_prep_hist -> k_colscan -> k_fill -> k_sumout  (4 launches).

#define NN 10000
#define ED 640000
#define D  128
#define NB 64                 // histogram blocks
#define EPB (ED / NB)         // 10000 edges per block (exact)
#define ST 192                // CSR slots per node (Poisson(64): safe)

typedef __bf16 bf16;
typedef bf16  bf16x8 __attribute__((ext_vector_type(8)));
typedef float f32x4  __attribute__((ext_vector_type(4)));

__device__ __forceinline__ bf16 f2b(float f) {
  unsigned u = __builtin_bit_cast(unsigned, f);
  u += 0x7fffu + ((u >> 16) & 1u);               // RTNE
  unsigned short h = (unsigned short)(u >> 16);
  return __builtin_bit_cast(bf16, h);
}

__device__ __forceinline__ bf16x8 bzero8() {
  bf16 z = __builtin_bit_cast(bf16, (unsigned short)0);
  bf16x8 v = {z, z, z, z, z, z, z, z};
  return v;
}

// ---------------------------------------------------------------------------
// K1: blocks 0..63: per-chunk LDS histogram of dst (LDS atomics, int4 I/O).
//     blocks 64..: x -> bf16; pack W1 (384x128), W2 (256x128) into MFMA
//     B-frag layout: Bp[((kb*8+t)*64+L)*8+j] = W[kb*32+(L>>4)*8+j][t*16+(L&15)]
// ---------------------------------------------------------------------------
__global__ __launch_bounds__(256) void k_prep_hist(const float* __restrict__ x,
                                                   const float* __restrict__ W1,
                                                   const float* __restrict__ W2,
                                                   const int*   __restrict__ dst,
                                                   bf16* __restrict__ xb,
                                                   bf16* __restrict__ W1p,
                                                   bf16* __restrict__ W2p,
                                                   int*  __restrict__ hist) {
  __shared__ __align__(16) int h[NN];
  int tid = threadIdx.x;
  if (blockIdx.x < NB) {                // ---- histogram part
    int b = blockIdx.x;
    int4 z4 = make_int4(0, 0, 0, 0);
    for (int i = tid; i < NN / 4; i += 256) ((int4*)h)[i] = z4;
    __syncthreads();
    const int4* d4 = (const int4*)(dst + b * EPB);
    for (int i = tid; i < EPB / 4; i += 256) {
      int4 dd = d4[i];
      atomicAdd(&h[dd.x], 1);
      atomicAdd(&h[dd.y], 1);
      atomicAdd(&h[dd.z], 1);
      atomicAdd(&h[dd.w], 1);
    }
    __syncthreads();
    int4* outp = (int4*)(hist + (size_t)b * NN);
    for (int i = tid; i < NN / 4; i += 256) outp[i] = ((const int4*)h)[i];
    return;
  }
  // ---- prep part
  int id = (blockIdx.x - NB) * 256 + tid;
  if (id < 160000) {                    // xb: 10000*128/8 chunks
    int i = id * 8;
    f32x4 a = *(const f32x4*)(x + i);
    f32x4 b = *(const f32x4*)(x + i + 4);
    bf16x8 hh;
    hh[0]=f2b(a[0]); hh[1]=f2b(a[1]); hh[2]=f2b(a[2]); hh[3]=f2b(a[3]);
    hh[4]=f2b(b[0]); hh[5]=f2b(b[1]); hh[6]=f2b(b[2]); hh[7]=f2b(b[3]);
    *(bf16x8*)(xb + i) = hh;
  } else if (id < 166144) {             // W1p: kb 0..11 (K=384)
    int o8 = id - 160000;
    int kb = o8 >> 9, rem = o8 & 511, t = rem >> 6, L = rem & 63;
    int col  = t * 16 + (L & 15);
    int row0 = kb * 32 + (L >> 4) * 8;
    bf16x8 hh;
    #pragma unroll
    for (int j = 0; j < 8; j++) hh[j] = f2b(W1[(row0 + j) * D + col]);
    *(bf16x8*)(W1p + o8 * 8) = hh;
  } else if (id < 170240) {             // W2p: kb 0..7 (K=256)
    int o8 = id - 166144;
    int kb = o8 >> 9, rem = o8 & 511, t = rem >> 6, L = rem & 63;
    int col  = t * 16 + (L & 15);
    int row0 = kb * 32 + (L >> 4) * 8;
    bf16x8 hh;
    #pragma unroll
    for (int j = 0; j < 8; j++) hh[j] = f2b(W2[(row0 + j) * D + col]);
    *(bf16x8*)(W2p + o8 * 8) = hh;
  }
}

// ---------------------------------------------------------------------------
// K2: per-node exclusive prefix over the NB block-partials (in place),
// total into counts. Coalesced across v.
// ---------------------------------------------------------------------------
__global__ __launch_bounds__(256) void k_colscan(int* __restrict__ hist,
                                                 int* __restrict__ counts) {
  int v = blockIdx.x * 256 + threadIdx.x;
  if (v >= NN) return;
  int run = 0;
  #pragma unroll
  for (int b = 0; b < NB; b++) {
    int t = hist[b * NN + v];
    hist[b * NN + v] = run;
    run += t;
  }
  counts[v] = run;
}

// ---------------------------------------------------------------------------
// K3: scatter edges into slotted CSR.  pos = d*ST + hist[b][d] + rank.
// rank via LDS fetch-add; no global atomics, no row_ptr.
// ---------------------------------------------------------------------------
__global__ __launch_bounds__(256) void k_fill(const int* __restrict__ src,
                                              const int* __restrict__ dst,
                                              const int* __restrict__ hist,
                                              int2* __restrict__ csr) {
  __shared__ __align__(16) int rk[NN];
  int b = blockIdx.x, tid = threadIdx.x;
  int4 z4 = make_int4(0, 0, 0, 0);
  for (int i = tid; i < NN / 4; i += 256) ((int4*)rk)[i] = z4;
  __syncthreads();
  int base = b * EPB;
  const int* __restrict__ hb = hist + (size_t)b * NN;
  const int4* d4 = (const int4*)(dst + base);
  const int4* s4 = (const int4*)(src + base);
  for (int i = tid; i < EPB / 4; i += 256) {
    int4 dd = d4[i];
    int4 ss = s4[i];
    int e = base + i * 4;
    {
      int r = atomicAdd(&rk[dd.x], 1);
      csr[(size_t)dd.x * ST + hb[dd.x] + r] = make_int2(e + 0, ss.x);
    }
    {
      int r = atomicAdd(&rk[dd.y], 1);
      csr[(size_t)dd.y * ST + hb[dd.y] + r] = make_int2(e + 1, ss.y);
    }
    {
      int r = atomicAdd(&rk[dd.z], 1);
      csr[(size_t)dd.z * ST + hb[dd.z] + r] = make_int2(e + 2, ss.z);
    }
    {
      int r = atomicAdd(&rk[dd.w], 1);
      csr[(size_t)dd.w * ST + hb[dd.w] + r] = make_int2(e + 3, ss.w);
    }
  }
}

// ---------------------------------------------------------------------------
// K4: fused segment-sum + two GEMMs. 512 threads / 8 waves / 32 nodes per
// block; 313 blocks.
//   phase A: wave w sums nodes n0+4w..n0+4w+3; lane = g*16+l; group g takes
//            edges g, g+4, ...; lane covers cols [8l,8l+8). ea/csr loads are
//            NON-TEMPORAL (read-once; keep xb L2-resident). After the
//            4-group shuffle reduce, groups 0/1/2 write bf16 sx / sea /
//            cnt*x straight into the LDS A1 tile (rounded once — same
//            numerics as the old sx->global->f2b path).
//   phase B: stage-1 GEMM  agg = A1[32x384] @ W1 + cnt*b1   (K=384)
//   phase C: stage-2 GEMM  out = [bf16(agg)|xb] @ W2 + b2   (K=256)
// A1 stride 392 bf16 (25.1 KB); A2 overlays, stride 264.
// ---------------------------------------------------------------------------
__global__ __launch_bounds__(512, 6) void k_sumout(const bf16*  __restrict__ xb,
                                                   const float* __restrict__ ea,
                                                   const int*   __restrict__ counts,
                                                   const int2*  __restrict__ csr,
                                                   const bf16*  __restrict__ W1p,
                                                   const bf16*  __restrict__ W2p,
                                                   const float* __restrict__ b1,
                                                   const float* __restrict__ b2,
                                                   float* __restrict__ out) {
  __shared__ __align__(16) bf16 lds[32 * 392];   // 25.1 KB
  int tid  = threadIdx.x;
  int w = tid >> 6, lane = tid & 63, quad = lane >> 4, l16 = lane & 15;
  int g = quad, l = l16;
  int n0 = blockIdx.x * 32;

  // ---- phase A: segment sums for 4 nodes per wave, results -> LDS A1
  for (int q = 0; q < 4; q++) {
    int m = w * 4 + q;
    int v = n0 + m;
    int cnt = (v < NN) ? counts[v] : 0;
    f32x4 ax0 = {0.f,0.f,0.f,0.f}, ax1 = {0.f,0.f,0.f,0.f};
    f32x4 ae0 = {0.f,0.f,0.f,0.f}, ae1 = {0.f,0.f,0.f,0.f};
    const int2* cbase = csr + (size_t)v * ST;
    #pragma unroll 2
    for (int e = g; e < cnt; e += 4) {
      long long cp = __builtin_nontemporal_load((const long long*)(cbase + e));
      int2 es = __builtin_bit_cast(int2, cp);
      const f32x4* ep = (const f32x4*)(ea + (size_t)es.x * D + l * 8);
      f32x4 f0 = __builtin_nontemporal_load(ep);
      f32x4 f1 = __builtin_nontemporal_load(ep + 1);
      bf16x8 hx = *(const bf16x8*)(xb + (size_t)es.y * D + l * 8);
      ax0[0] += (float)hx[0]; ax0[1] += (float)hx[1];
      ax0[2] += (float)hx[2]; ax0[3] += (float)hx[3];
      ax1[0] += (float)hx[4]; ax1[1] += (float)hx[5];
      ax1[2] += (float)hx[6]; ax1[3] += (float)hx[7];
      ae0 += f0;
      ae1 += f1;
    }
    #pragma unroll
    for (int i = 0; i < 4; i++) {
      ax0[i] += __shfl_xor(ax0[i], 16, 64); ax0[i] += __shfl_xor(ax0[i], 32, 64);
      ax1[i] += __shfl_xor(ax1[i], 16, 64); ax1[i] += __shfl_xor(ax1[i], 32, 64);
      ae0[i] += __shfl_xor(ae0[i], 16, 64); ae0[i] += __shfl_xor(ae0[i], 32, 64);
      ae1[i] += __shfl_xor(ae1[i], 16, 64); ae1[i] += __shfl_xor(ae1[i], 32, 64);
    }
    // groups write A1[m]: g0 -> sx cols [0,128); g1 -> sea cols [256,384);
    // g2 -> cnt*x cols [128,256); g3 idle.
    if (g == 0) {
      bf16x8 h;
      h[0]=f2b(ax0[0]); h[1]=f2b(ax0[1]); h[2]=f2b(ax0[2]); h[3]=f2b(ax0[3]);
      h[4]=f2b(ax1[0]); h[5]=f2b(ax1[1]); h[6]=f2b(ax1[2]); h[7]=f2b(ax1[3]);
      *(bf16x8*)&lds[m * 392 + l * 8] = h;
    } else if (g == 1) {
      bf16x8 h;
      h[0]=f2b(ae0[0]); h[1]=f2b(ae0[1]); h[2]=f2b(ae0[2]); h[3]=f2b(ae0[3]);
      h[4]=f2b(ae1[0]); h[5]=f2b(ae1[1]); h[6]=f2b(ae1[2]); h[7]=f2b(ae1[3]);
      *(bf16x8*)&lds[m * 392 + 256 + l * 8] = h;
    } else if (g == 2) {
      float cntf = (float)cnt;
      bf16x8 hx = (v < NN) ? *(const bf16x8*)(xb + (size_t)v * D + l * 8) : bzero8();
      bf16x8 h;
      #pragma unroll
      for (int k = 0; k < 8; k++) h[k] = f2b((float)hx[k] * cntf);
      *(bf16x8*)&lds[m * 392 + 128 + l * 8] = h;
    }
  }
  __syncthreads();

  // ---- phase B: stage-1 GEMM (M=32, K=384). wave -> (mh = w>>2, nc = w&3)
  int mh = w >> 2, nc = w & 3;
  f32x4 acc0 = {0.f,0.f,0.f,0.f}, acc1 = {0.f,0.f,0.f,0.f};
  #pragma unroll
  for (int kb = 0; kb < 12; kb++) {
    bf16x8 B0 = *(const bf16x8*)(W1p + ((kb * 8 + nc * 2 + 0) * 64 + lane) * 8);
    bf16x8 B1 = *(const bf16x8*)(W1p + ((kb * 8 + nc * 2 + 1) * 64 + lane) * 8);
    bf16x8 a = *(const bf16x8*)&lds[(mh * 16 + l16) * 392 + kb * 32 + quad * 8];
    acc0 = __builtin_amdgcn_mfma_f32_16x16x32_bf16(a, B0, acc0, 0, 0, 0);
    acc1 = __builtin_amdgcn_mfma_f32_16x16x32_bf16(a, B1, acc1, 0, 0, 0);
  }
  __syncthreads();                      // all A1 reads done; lds reused as A2

  // ---- epilogue-1: agg = acc + cnt*b1 -> bf16 into A2 cols [0,128), stride 264
  float cr[4];
  #pragma unroll
  for (int r = 0; r < 4; r++) {
    int v = n0 + mh * 16 + quad * 4 + r;
    cr[r] = (v < NN) ? (float)counts[v] : 0.f;
  }
  #pragma unroll
  for (int tt = 0; tt < 2; tt++) {
    int col = nc * 32 + tt * 16 + l16;
    float bb = b1[col];
    f32x4 av = tt ? acc1 : acc0;
    #pragma unroll
    for (int r = 0; r < 4; r++) {
      int m = mh * 16 + quad * 4 + r;
      lds[m * 264 + col] = f2b(av[r] + cr[r] * bb);
    }
  }
  // ---- A2 cols [128,256) = xb
  {
    int m2 = tid >> 4, c = tid & 15;
    int v2 = n0 + m2;
    bf16x8 h = (v2 < NN) ? *(const bf16x8*)(xb + (size_t)v2 * D + c * 8) : bzero8();
    *(bf16x8*)&lds[m2 * 264 + 128 + c * 8] = h;
  }
  __syncthreads();

  // ---- phase C: stage-2 GEMM (K=256)
  f32x4 acc2a = {0.f,0.f,0.f,0.f}, acc2b = {0.f,0.f,0.f,0.f};
  #pragma unroll
  for (int kb = 0; kb < 8; kb++) {
    bf16x8 B0 = *(const bf16x8*)(W2p + ((kb * 8 + nc * 2 + 0) * 64 + lane) * 8);
    bf16x8 B1 = *(const bf16x8*)(W2p + ((kb * 8 + nc * 2 + 1) * 64 + lane) * 8);
    bf16x8 a = *(const bf16x8*)&lds[(mh * 16 + l16) * 264 + kb * 32 + quad * 8];
    acc2a = __builtin_amdgcn_mfma_f32_16x16x32_bf16(a, B0, acc2a, 0, 0, 0);
    acc2b = __builtin_amdgcn_mfma_f32_16x16x32_bf16(a, B1, acc2b, 0, 0, 0);
  }

  #pragma unroll
  for (int tt = 0; tt < 2; tt++) {
    int col = nc * 32 + tt * 16 + l16;
    float bb = b2[col];
    f32x4 av = tt ? acc2b : acc2a;
    #pragma unroll
    for (int r = 0; r < 4; r++) {
      int v = n0 + mh * 16 + quad * 4 + r;
      if (v < NN) out[(size_t)v * D + col] = av[r] + bb;
    }
  }
}

// ---------------------------------------------------------------------------
extern "C" void kernel_launch(void* const* d_in, const int* in_sizes, int n_in,
                              void* d_out, int out_size, void* d_ws, size_t ws_size,
                              hipStream_t stream) {
  const float* x  = (const float*)d_in[0];
  const int*   ei = (const int*)  d_in[1];   // [2, E]: src = ei, dst = ei + ED
  const float* ea = (const float*)d_in[2];
  const float* W1 = (const float*)d_in[3];
  const float* b1 = (const float*)d_in[4];
  const float* W2 = (const float*)d_in[5];
  const float* b2 = (const float*)d_in[6];
  float* out = (float*)d_out;

  char* ws = (char*)d_ws;
  size_t off = 0;
  auto alloc = [&](size_t bytes) -> void* {
    void* p = ws + off;
    off += (bytes + 255) & ~(size_t)255;
    return p;
  };
  bf16*  xb      = (bf16*)alloc((size_t)NN * D * 2);
  bf16*  W1p     = (bf16*)alloc(49152 * 2);       // 384*128
  bf16*  W2p     = (bf16*)alloc(32768 * 2);       // 256*128
  int*   counts  = (int*)alloc(NN * 4);
  int*   hist    = (int*)alloc((size_t)NB * NN * 4);   // 2.56 MB block-partials
  int2*  csr     = (int2*)alloc((size_t)NN * ST * 8);  // 15.4 MB slotted CSR
  (void)ws_size; (void)in_sizes; (void)n_in; (void)out_size;  // ~21 MB

  const int* src = ei;
  const int* dst = ei + ED;

  k_prep_hist<<<NB + 665, 256, 0, stream>>>(x, W1, W2, dst, xb, W1p, W2p, hist);
  k_colscan<<<40, 256, 0, stream>>>(hist, counts);
  k_fill<<<NB, 256, 0, stream>>>(src, dst, hist, csr);
  k_sumout<<<313, 512, 0, stream>>>(xb, ea, counts, csr, W1p, W2p, b1, b2, out);
}

// Round 4
// 510.903 us; speedup vs baseline: 1.0768x; 1.0768x over previous
//
#include <hip/hip_runtime.h>

// Node2Edge2Node GNN block, MI355X (gfx950) — R7: R5 parallelism + R6 wins.
//
//   agg[v] = (Σ_{e->v} x[src_e]) @ W1a  +  cnt_v * (x[v] @ W1b)
//          + (Σ_{e->v} ea_e)    @ W1c  +  cnt_v * b1
//   out    = [agg | x] @ W2 + b2
//
// R6 post-mortem: fusing k_sum into the GEMM kernel cut wave-parallelism on
// the BW-critical ea gather 4x (10000 -> 2504 waves) and added a straggler
// barrier -> +30us. R7 reverts that; keeps prep+hist fusion, slotted CSR
// (no global scan), vectorized fill, nt loads. sx/sea now use nt stores
// (read-once by k_out) to preserve xb L2 residency.
// Pipeline: k_prep_hist -> k_colscan -> k_fill -> k_sum -> k_out (5 launches).

#define NN 10000
#define ED 640000
#define D  128
#define NB 64                 // histogram blocks
#define EPB (ED / NB)         // 10000 edges per block (exact)
#define ST 192                // CSR slots per node (Poisson(64): P(>192)~1e-30)

typedef __bf16 bf16;
typedef bf16  bf16x8 __attribute__((ext_vector_type(8)));
typedef float f32x4  __attribute__((ext_vector_type(4)));

__device__ __forceinline__ bf16 f2b(float f) {
  unsigned u = __builtin_bit_cast(unsigned, f);
  u += 0x7fffu + ((u >> 16) & 1u);               // RTNE
  unsigned short h = (unsigned short)(u >> 16);
  return __builtin_bit_cast(bf16, h);
}

__device__ __forceinline__ bf16x8 bzero8() {
  bf16 z = __builtin_bit_cast(bf16, (unsigned short)0);
  bf16x8 v = {z, z, z, z, z, z, z, z};
  return v;
}

// ---------------------------------------------------------------------------
// K1: blocks 0..63: per-chunk LDS histogram of dst (LDS atomics, int4 I/O).
//     blocks 64..: x -> bf16; pack W1 (384x128), W2 (256x128) into MFMA
//     B-frag layout: Bp[((kb*8+t)*64+L)*8+j] = W[kb*32+(L>>4)*8+j][t*16+(L&15)]
// ---------------------------------------------------------------------------
__global__ __launch_bounds__(256) void k_prep_hist(const float* __restrict__ x,
                                                   const float* __restrict__ W1,
                                                   const float* __restrict__ W2,
                                                   const int*   __restrict__ dst,
                                                   bf16* __restrict__ xb,
                                                   bf16* __restrict__ W1p,
                                                   bf16* __restrict__ W2p,
                                                   int*  __restrict__ hist) {
  __shared__ __align__(16) int h[NN];
  int tid = threadIdx.x;
  if (blockIdx.x < NB) {                // ---- histogram part
    int b = blockIdx.x;
    int4 z4 = make_int4(0, 0, 0, 0);
    for (int i = tid; i < NN / 4; i += 256) ((int4*)h)[i] = z4;
    __syncthreads();
    const int4* d4 = (const int4*)(dst + b * EPB);
    for (int i = tid; i < EPB / 4; i += 256) {
      int4 dd = d4[i];
      atomicAdd(&h[dd.x], 1);
      atomicAdd(&h[dd.y], 1);
      atomicAdd(&h[dd.z], 1);
      atomicAdd(&h[dd.w], 1);
    }
    __syncthreads();
    int4* outp = (int4*)(hist + (size_t)b * NN);
    for (int i = tid; i < NN / 4; i += 256) outp[i] = ((const int4*)h)[i];
    return;
  }
  // ---- prep part
  int id = (blockIdx.x - NB) * 256 + tid;
  if (id < 160000) {                    // xb: 10000*128/8 chunks
    int i = id * 8;
    f32x4 a = *(const f32x4*)(x + i);
    f32x4 b = *(const f32x4*)(x + i + 4);
    bf16x8 hh;
    hh[0]=f2b(a[0]); hh[1]=f2b(a[1]); hh[2]=f2b(a[2]); hh[3]=f2b(a[3]);
    hh[4]=f2b(b[0]); hh[5]=f2b(b[1]); hh[6]=f2b(b[2]); hh[7]=f2b(b[3]);
    *(bf16x8*)(xb + i) = hh;
  } else if (id < 166144) {             // W1p: kb 0..11 (K=384)
    int o8 = id - 160000;
    int kb = o8 >> 9, rem = o8 & 511, t = rem >> 6, L = rem & 63;
    int col  = t * 16 + (L & 15);
    int row0 = kb * 32 + (L >> 4) * 8;
    bf16x8 hh;
    #pragma unroll
    for (int j = 0; j < 8; j++) hh[j] = f2b(W1[(row0 + j) * D + col]);
    *(bf16x8*)(W1p + o8 * 8) = hh;
  } else if (id < 170240) {             // W2p: kb 0..7 (K=256)
    int o8 = id - 166144;
    int kb = o8 >> 9, rem = o8 & 511, t = rem >> 6, L = rem & 63;
    int col  = t * 16 + (L & 15);
    int row0 = kb * 32 + (L >> 4) * 8;
    bf16x8 hh;
    #pragma unroll
    for (int j = 0; j < 8; j++) hh[j] = f2b(W2[(row0 + j) * D + col]);
    *(bf16x8*)(W2p + o8 * 8) = hh;
  }
}

// ---------------------------------------------------------------------------
// K2: per-node exclusive prefix over the NB block-partials (in place),
// total into counts. Coalesced across v.
// ---------------------------------------------------------------------------
__global__ __launch_bounds__(256) void k_colscan(int* __restrict__ hist,
                                                 int* __restrict__ counts) {
  int v = blockIdx.x * 256 + threadIdx.x;
  if (v >= NN) return;
  int run = 0;
  #pragma unroll
  for (int b = 0; b < NB; b++) {
    int t = hist[b * NN + v];
    hist[b * NN + v] = run;
    run += t;
  }
  counts[v] = run;
}

// ---------------------------------------------------------------------------
// K3: scatter edges into slotted CSR.  pos = d*ST + hist[b][d] + rank.
// rank via LDS fetch-add; no global atomics.
// ---------------------------------------------------------------------------
__global__ __launch_bounds__(256) void k_fill(const int* __restrict__ src,
                                              const int* __restrict__ dst,
                                              const int* __restrict__ hist,
                                              int2* __restrict__ csr) {
  __shared__ __align__(16) int rk[NN];
  int b = blockIdx.x, tid = threadIdx.x;
  int4 z4 = make_int4(0, 0, 0, 0);
  for (int i = tid; i < NN / 4; i += 256) ((int4*)rk)[i] = z4;
  __syncthreads();
  int base = b * EPB;
  const int* __restrict__ hb = hist + (size_t)b * NN;
  const int4* d4 = (const int4*)(dst + base);
  const int4* s4 = (const int4*)(src + base);
  for (int i = tid; i < EPB / 4; i += 256) {
    int4 dd = d4[i];
    int4 ss = s4[i];
    int e = base + i * 4;
    {
      int r = atomicAdd(&rk[dd.x], 1);
      csr[(size_t)dd.x * ST + hb[dd.x] + r] = make_int2(e + 0, ss.x);
    }
    {
      int r = atomicAdd(&rk[dd.y], 1);
      csr[(size_t)dd.y * ST + hb[dd.y] + r] = make_int2(e + 1, ss.y);
    }
    {
      int r = atomicAdd(&rk[dd.z], 1);
      csr[(size_t)dd.z * ST + hb[dd.z] + r] = make_int2(e + 2, ss.z);
    }
    {
      int r = atomicAdd(&rk[dd.w], 1);
      csr[(size_t)dd.w * ST + hb[dd.w] + r] = make_int2(e + 3, ss.w);
    }
  }
}

// ---------------------------------------------------------------------------
// K4: per-node segment sums. sx[v] = Σ x[src_e] (fp32), sea[v] = Σ ea_e.
// One wave per node (10000 waves: max TLP for the 327MB ea stream).
// Lane = g*16+l: group g handles edges g, g+4, ...; lane covers cols
// [8l,8l+8). ea/csr loads NON-TEMPORAL (read-once; keep xb L2-resident).
// sx/sea stores NON-TEMPORAL (read-once by k_out; don't evict xb).
// ---------------------------------------------------------------------------
__global__ __launch_bounds__(256) void k_sum(const bf16*  __restrict__ xb,
                                             const float* __restrict__ ea,
                                             const int*   __restrict__ counts,
                                             const int2*  __restrict__ csr,
                                             float* __restrict__ sx,
                                             float* __restrict__ sea) {
  int gwave = (blockIdx.x * 256 + threadIdx.x) >> 6;   // 0..9999
  if (gwave >= NN) return;
  int lane = threadIdx.x & 63;
  int g = lane >> 4, l = lane & 15;
  int cnt = counts[gwave];
  const int2* cbase = csr + (size_t)gwave * ST;

  f32x4 ax0 = {0.f,0.f,0.f,0.f}, ax1 = {0.f,0.f,0.f,0.f};
  f32x4 ae0 = {0.f,0.f,0.f,0.f}, ae1 = {0.f,0.f,0.f,0.f};

  #pragma unroll 2
  for (int e = g; e < cnt; e += 4) {
    long long cp = __builtin_nontemporal_load((const long long*)(cbase + e));
    int2 es = __builtin_bit_cast(int2, cp);
    const f32x4* ep = (const f32x4*)(ea + (size_t)es.x * D + l * 8);
    f32x4 f0 = __builtin_nontemporal_load(ep);
    f32x4 f1 = __builtin_nontemporal_load(ep + 1);
    bf16x8 hx = *(const bf16x8*)(xb + (size_t)es.y * D + l * 8);
    ax0[0] += (float)hx[0]; ax0[1] += (float)hx[1];
    ax0[2] += (float)hx[2]; ax0[3] += (float)hx[3];
    ax1[0] += (float)hx[4]; ax1[1] += (float)hx[5];
    ax1[2] += (float)hx[6]; ax1[3] += (float)hx[7];
    ae0 += f0;
    ae1 += f1;
  }
  // reduce across the 4 groups (lane bits 4,5)
  #pragma unroll
  for (int i = 0; i < 4; i++) {
    ax0[i] += __shfl_xor(ax0[i], 16, 64); ax0[i] += __shfl_xor(ax0[i], 32, 64);
    ax1[i] += __shfl_xor(ax1[i], 16, 64); ax1[i] += __shfl_xor(ax1[i], 32, 64);
    ae0[i] += __shfl_xor(ae0[i], 16, 64); ae0[i] += __shfl_xor(ae0[i], 32, 64);
    ae1[i] += __shfl_xor(ae1[i], 16, 64); ae1[i] += __shfl_xor(ae1[i], 32, 64);
  }
  if (lane < 16) {
    f32x4* px = (f32x4*)(sx  + (size_t)gwave * D + l * 8);
    f32x4* pe = (f32x4*)(sea + (size_t)gwave * D + l * 8);
    __builtin_nontemporal_store(ax0, px);
    __builtin_nontemporal_store(ax1, px + 1);
    __builtin_nontemporal_store(ae0, pe);
    __builtin_nontemporal_store(ae1, pe + 1);
  }
}

// ---------------------------------------------------------------------------
// K5: fused per-node GEMMs.  64 nodes/block, 157 blocks.
//   stage1: agg = [sx | cnt*x | sea] @ W1 + cnt*b1          (K=384)
//   stage2: out = [bf16(agg) | xb] @ W2 + b2                (K=256)
// One LDS buffer reused: A1 stride 392 bf16, A2 stride 264 bf16.
// ---------------------------------------------------------------------------
__global__ __launch_bounds__(256) void k_out(const float* __restrict__ sx,
                                             const float* __restrict__ sea,
                                             const bf16*  __restrict__ xb,
                                             const bf16*  __restrict__ W1p,
                                             const bf16*  __restrict__ W2p,
                                             const float* __restrict__ b1,
                                             const float* __restrict__ b2,
                                             const int*   __restrict__ counts,
                                             float* __restrict__ out) {
  __shared__ __align__(16) bf16 lds[64 * 392];   // 50.2 KB
  int tid  = threadIdx.x;
  int wave = tid >> 6, lane = tid & 63, quad = lane >> 4, l16 = lane & 15;
  int n0 = blockIdx.x * 64;

  // ---- stage-1 staging: A1[m][*] = [sx | cnt*x | sea] bf16, stride 392
  #pragma unroll
  for (int i = 0; i < 4; i++) {
    int m = (tid >> 4) + 16 * i;
    int v = n0 + m;
    int cl = tid & 15;
    float cntf = (v < NN) ? (float)counts[v] : 0.f;
    #pragma unroll
    for (int j = 0; j < 3; j++) {
      int c = cl + 16 * j;              // chunk 0..47
      bf16x8 h;
      if (v < NN) {
        if (j == 0) {
          const f32x4* p = (const f32x4*)(sx + (size_t)v * D + cl * 8);
          f32x4 f0 = __builtin_nontemporal_load(p);
          f32x4 f1 = __builtin_nontemporal_load(p + 1);
          h[0]=f2b(f0[0]); h[1]=f2b(f0[1]); h[2]=f2b(f0[2]); h[3]=f2b(f0[3]);
          h[4]=f2b(f1[0]); h[5]=f2b(f1[1]); h[6]=f2b(f1[2]); h[7]=f2b(f1[3]);
        } else if (j == 1) {
          bf16x8 hx = *(const bf16x8*)(xb + (size_t)v * D + cl * 8);
          #pragma unroll
          for (int k = 0; k < 8; k++) h[k] = f2b((float)hx[k] * cntf);
        } else {
          const f32x4* p = (const f32x4*)(sea + (size_t)v * D + cl * 8);
          f32x4 f0 = __builtin_nontemporal_load(p);
          f32x4 f1 = __builtin_nontemporal_load(p + 1);
          h[0]=f2b(f0[0]); h[1]=f2b(f0[1]); h[2]=f2b(f0[2]); h[3]=f2b(f0[3]);
          h[4]=f2b(f1[0]); h[5]=f2b(f1[1]); h[6]=f2b(f1[2]); h[7]=f2b(f1[3]);
        }
      } else h = bzero8();
      *(bf16x8*)&lds[m * 392 + c * 8] = h;
    }
  }
  __syncthreads();

  // ---- stage-1 GEMM (K=384)
  f32x4 acc[4][2];
  #pragma unroll
  for (int mt = 0; mt < 4; mt++)
    #pragma unroll
    for (int tt = 0; tt < 2; tt++) acc[mt][tt] = (f32x4){0.f, 0.f, 0.f, 0.f};

  #pragma unroll
  for (int kb = 0; kb < 12; kb++) {
    bf16x8 B0 = *(const bf16x8*)(W1p + ((kb * 8 + wave * 2 + 0) * 64 + lane) * 8);
    bf16x8 B1 = *(const bf16x8*)(W1p + ((kb * 8 + wave * 2 + 1) * 64 + lane) * 8);
    #pragma unroll
    for (int mt = 0; mt < 4; mt++) {
      bf16x8 a = *(const bf16x8*)&lds[(mt * 16 + l16) * 392 + kb * 32 + quad * 8];
      acc[mt][0] = __builtin_amdgcn_mfma_f32_16x16x32_bf16(a, B0, acc[mt][0], 0, 0, 0);
      acc[mt][1] = __builtin_amdgcn_mfma_f32_16x16x32_bf16(a, B1, acc[mt][1], 0, 0, 0);
    }
  }
  __syncthreads();                      // all A1 reads done; lds reused as A2

  // ---- epilogue-1: agg = acc + cnt*b1 -> bf16 into A2 cols [0,128), stride 264
  #pragma unroll
  for (int tt = 0; tt < 2; tt++) {
    int col = wave * 32 + tt * 16 + l16;
    float bb = b1[col];
    #pragma unroll
    for (int mt = 0; mt < 4; mt++)
      #pragma unroll
      for (int r = 0; r < 4; r++) {
        int m = mt * 16 + quad * 4 + r;
        int v = n0 + m;
        float cntf = (v < NN) ? (float)counts[v] : 0.f;
        lds[m * 264 + col] = f2b(acc[mt][tt][r] + cntf * bb);
      }
  }
  // ---- A2 cols [128,256) = xb
  #pragma unroll
  for (int i = 0; i < 4; i++) {
    int m = (tid >> 4) + 16 * i;
    int c = tid & 15;
    int v = n0 + m;
    bf16x8 h = (v < NN) ? *(const bf16x8*)(xb + (size_t)v * D + c * 8) : bzero8();
    *(bf16x8*)&lds[m * 264 + 128 + c * 8] = h;
  }
  __syncthreads();

  // ---- stage-2 GEMM (K=256)
  f32x4 acc2[4][2];
  #pragma unroll
  for (int mt = 0; mt < 4; mt++)
    #pragma unroll
    for (int tt = 0; tt < 2; tt++) acc2[mt][tt] = (f32x4){0.f, 0.f, 0.f, 0.f};

  #pragma unroll
  for (int kb = 0; kb < 8; kb++) {
    bf16x8 B0 = *(const bf16x8*)(W2p + ((kb * 8 + wave * 2 + 0) * 64 + lane) * 8);
    bf16x8 B1 = *(const bf16x8*)(W2p + ((kb * 8 + wave * 2 + 1) * 64 + lane) * 8);
    #pragma unroll
    for (int mt = 0; mt < 4; mt++) {
      bf16x8 a = *(const bf16x8*)&lds[(mt * 16 + l16) * 264 + kb * 32 + quad * 8];
      acc2[mt][0] = __builtin_amdgcn_mfma_f32_16x16x32_bf16(a, B0, acc2[mt][0], 0, 0, 0);
      acc2[mt][1] = __builtin_amdgcn_mfma_f32_16x16x32_bf16(a, B1, acc2[mt][1], 0, 0, 0);
    }
  }

  #pragma unroll
  for (int tt = 0; tt < 2; tt++) {
    int col = wave * 32 + tt * 16 + l16;
    float bb = b2[col];
    #pragma unroll
    for (int mt = 0; mt < 4; mt++)
      #pragma unroll
      for (int r = 0; r < 4; r++) {
        int v = n0 + mt * 16 + quad * 4 + r;
        if (v < NN) out[(size_t)v * D + col] = acc2[mt][tt][r] + bb;
      }
  }
}

// ---------------------------------------------------------------------------
extern "C" void kernel_launch(void* const* d_in, const int* in_sizes, int n_in,
                              void* d_out, int out_size, void* d_ws, size_t ws_size,
                              hipStream_t stream) {
  const float* x  = (const float*)d_in[0];
  const int*   ei = (const int*)  d_in[1];   // [2, E]: src = ei, dst = ei + ED
  const float* ea = (const float*)d_in[2];
  const float* W1 = (const float*)d_in[3];
  const float* b1 = (const float*)d_in[4];
  const float* W2 = (const float*)d_in[5];
  const float* b2 = (const float*)d_in[6];
  float* out = (float*)d_out;

  char* ws = (char*)d_ws;
  size_t off = 0;
  auto alloc = [&](size_t bytes) -> void* {
    void* p = ws + off;
    off += (bytes + 255) & ~(size_t)255;
    return p;
  };
  bf16*  xb      = (bf16*)alloc((size_t)NN * D * 2);
  bf16*  W1p     = (bf16*)alloc(49152 * 2);       // 384*128
  bf16*  W2p     = (bf16*)alloc(32768 * 2);       // 256*128
  float* sx      = (float*)alloc((size_t)NN * D * 4);
  float* sea     = (float*)alloc((size_t)NN * D * 4);
  int*   counts  = (int*)alloc(NN * 4);
  int*   hist    = (int*)alloc((size_t)NB * NN * 4);   // 2.56 MB block-partials
  int2*  csr     = (int2*)alloc((size_t)NN * ST * 8);  // 15.4 MB slotted CSR
  (void)ws_size; (void)in_sizes; (void)n_in; (void)out_size;  // ~31 MB

  const int* src = ei;
  const int* dst = ei + ED;

  k_prep_hist<<<NB + 665, 256, 0, stream>>>(x, W1, W2, dst, xb, W1p, W2p, hist);
  k_colscan<<<40, 256, 0, stream>>>(hist, counts);
  k_fill<<<NB, 256, 0, stream>>>(src, dst, hist, csr);
  k_sum<<<2500, 256, 0, stream>>>(xb, ea, counts, csr, sx, sea);
  k_out<<<157, 256, 0, stream>>>(sx, sea, xb, W1p, W2p, b1, b2, counts, out);
}